// Round 16
// baseline (22.223 us; speedup 1.0000x reference)
//
#include <hip/hip_runtime.h>
#include <math.h>

#define NB 4096
#define ND 128
#define TI 128        // i-rows per block
#define TJ 256        // j-cols per block
#define NCS (NB / TJ) // 16 column splits (partials contributors per row)

typedef float f32x4 __attribute__((ext_vector_type(4)));

// ---- pass 1: fused normalize + fp8 128x256 LDS sim-tile + MFMA + stats ------
// fp8-e4m3 staging halves LDS vs bf16: At 16 KB + Bt 32 KB + red 3 KB = 51 KB
// -> 2 blocks/CU (512 blocks x 512 thr, 16 waves/CU): independent blocks'
// stage/barrier/compute phases interleave on the CU (TLP stall-filling).
// LDS layout (8B chunks of 8 fp8): (row, c8) -> slot row*16 + (c8 ^ (row&15))
//   -> write (lanes vary c8) and fragment read (lanes vary row) conflict-free.
// Swapped MFMA operands: acc = mfma(j_frag, i_frag); fp8 16x16x32 C/D layout
// is shape-determined (same as bf16): D col (lane&15) = i index -> stats
// accumulate in-thread; cross-lane reduce = offsets 16/32 only.
// Wave shape = R12's verified optimum: wr = wid>>1 (4 x 32 i-rows, it=2),
// wc = wid&1 (2 x 128 j-cols, jt=8).
__global__ __launch_bounds__(512) void supcon_mfma(
    const float* __restrict__ f, const int* __restrict__ labels,
    float* __restrict__ partials, float* __restrict__ out)
{
    __shared__ __align__(16) long At[TI * 16];     // 16 KB (i rows, fp8)
    __shared__ __align__(16) long Bt[TJ * 16];     // 32 KB (j rows, fp8)
    __shared__ float redL[2][TI][3];               // 3 KB

    const int t    = threadIdx.x;
    const int lane = t & 63;
    const int wid  = t >> 6;            // 0..7
    const int wr   = wid >> 1;          // 0..3 : i rows wr*32 .. +32
    const int wc   = wid & 1;           // 0..1 : j cols wc*128 .. +128
    const int bi   = blockIdx.x >> 4;   // i tile 0..31
    const int cs   = blockIdx.x & 15;   // j tile 0..15
    const int lr   = lane & 15;
    const int lk   = lane >> 4;
    const int ib   = bi * TI;
    const int jb   = cs * TJ;

    if (blockIdx.x == 0 && t == 0) out[0] = 0.f;   // target of final's atomics

    // ---- stage + normalize both tiles (f32 -> fp8 e4m3, XOR-swizzled) -------
    // Deterministic recompute: same per-row op order in every block.
    {
        const int c8 = t & 15;          // 8B chunk (8 fp8) within row
        const int rl = t >> 4;          // 0..31
        const float* gA = f + (size_t)ib * ND;
        const float* gB = f + (size_t)jb * ND;
#pragma unroll
        for (int s = 0; s < 2; ++s) {
            const float* g = s ? gB : gA;
            long*        T = s ? Bt : At;
            const int    nr = s ? (TJ / 32) : (TI / 32);
            for (int p = 0; p < nr; ++p) {
                const int row = p * 32 + rl;
                const float4 lo = *reinterpret_cast<const float4*>(g + row * ND + c8 * 8);
                const float4 hi = *reinterpret_cast<const float4*>(g + row * ND + c8 * 8 + 4);
                float ss = lo.x*lo.x + lo.y*lo.y + lo.z*lo.z + lo.w*lo.w
                         + hi.x*hi.x + hi.y*hi.y + hi.z*hi.z + hi.w*hi.w;
#pragma unroll
                for (int off = 1; off < 16; off <<= 1) ss += __shfl_xor(ss, off, 64);
                const float inv = 1.0f / fmaxf(sqrtf(ss), 1e-12f);
                int w0 = __builtin_amdgcn_cvt_pk_fp8_f32(lo.x * inv, lo.y * inv, 0, false);
                w0     = __builtin_amdgcn_cvt_pk_fp8_f32(lo.z * inv, lo.w * inv, w0, true);
                int w1 = __builtin_amdgcn_cvt_pk_fp8_f32(hi.x * inv, hi.y * inv, 0, false);
                w1     = __builtin_amdgcn_cvt_pk_fp8_f32(hi.z * inv, hi.w * inv, w1, true);
                int2 pk; pk.x = w0; pk.y = w1;
                *reinterpret_cast<int2*>(&T[row * 16 + (c8 ^ (row & 15))]) = pk;
            }
        }
    }

    // my i indices / labels (overlap staging latency)
    int ig[2], labi[2];
#pragma unroll
    for (int it = 0; it < 2; ++it) {
        ig[it]   = ib + wr * 32 + it * 16 + lr;   // D col = lane&15
        labi[it] = labels[ig[it]];
    }

    __syncthreads();

    // preload i-side fragments (MFMA B operand): one ds_read_b64 each
    long bfr[2][4];
#pragma unroll
    for (int it = 0; it < 2; ++it)
#pragma unroll
        for (int ks = 0; ks < 4; ++ks) {
            const int row = wr * 32 + it * 16 + lr;
            bfr[it][ks] = At[row * 16 + ((ks * 4 + lk) ^ (row & 15))];
        }

    float es[2] = {}, ps[2] = {}, np[2] = {};

#pragma unroll
    for (int jt = 0; jt < 8; ++jt) {
        // j-side fragments (MFMA A operand)
        long af[4];
#pragma unroll
        for (int ks = 0; ks < 4; ++ks) {
            const int row = wc * 128 + jt * 16 + lr;
            af[ks] = Bt[row * 16 + ((ks * 4 + lk) ^ (row & 15))];
        }
        f32x4 acc[2] = {};
#pragma unroll
        for (int ks = 0; ks < 4; ++ks)
#pragma unroll
            for (int it = 0; it < 2; ++it)
                acc[it] = __builtin_amdgcn_mfma_f32_16x16x32_fp8_fp8(
                    af[ks], bfr[it][ks], acc[it], 0, 0, 0);

        // j labels for this 16-tile: contiguous int4 per lk group
        const int jg0 = jb + wc * 128 + jt * 16 + lk * 4;   // D row = lk*4 + r
        const int4 lj4 = *reinterpret_cast<const int4*>(&labels[jg0]);
        const int lj[4] = {lj4.x, lj4.y, lj4.z, lj4.w};

        // epilogue: D[row = j-local = lk*4+r][col = i-local = lr]
#pragma unroll
        for (int it = 0; it < 2; ++it)
#pragma unroll
            for (int r = 0; r < 4; ++r) {
                const int   jgv  = jg0 + r;
                const float s    = acc[it][r];
                const float e    = __expf(s);
                const bool  self = (jgv == ig[it]);
                const bool  pos  = (lj[r] == labi[it]) && !self;
                es[it] += self ? 0.f : e;
                ps[it] += pos ? s : 0.f;
                np[it] += pos ? 1.f : 0.f;
            }
    }

    // cross-lane reduce over the 4 lk-groups only (offsets 16, 32)
#pragma unroll
    for (int off = 16; off < 64; off <<= 1)
#pragma unroll
        for (int it = 0; it < 2; ++it) {
            es[it] += __shfl_xor(es[it], off, 64);
            ps[it] += __shfl_xor(ps[it], off, 64);
            np[it] += __shfl_xor(np[it], off, 64);
        }
    if (lk == 0) {
#pragma unroll
        for (int it = 0; it < 2; ++it) {
            const int rl = wr * 32 + it * 16 + lr;
            redL[wc][rl][0] = es[it];
            redL[wc][rl][1] = ps[it];
            redL[wc][rl][2] = np[it];
        }
    }
    __syncthreads();
    if (t < TI) {   // fold the 2 col-halves; one deterministic writer per (cs,row)
        float* p = partials + ((size_t)cs * NB + ib + t) * 3;
        p[0] = redL[0][t][0] + redL[1][t][0];
        p[1] = redL[0][t][1] + redL[1][t][1];
        p[2] = redL[0][t][2] + redL[1][t][2];
    }
}

// ---- pass 2: per-row loss + block-level reduce + atomic to out --------------
__global__ __launch_bounds__(256) void final_kernel(
    const float* __restrict__ partials, float* __restrict__ out)
{
    const int row = blockIdx.x * 256 + threadIdx.x;
    float es = 0.f, ps = 0.f, np = 0.f;
#pragma unroll
    for (int cs = 0; cs < NCS; ++cs) {
        const float* p = partials + ((size_t)cs * NB + row) * 3;
        es += p[0]; ps += p[1]; np += p[2];
    }
    const float lse = logf(es);
    float c = -(ps - np * lse) / ((np + 1e-5f) * (float)NB);
#pragma unroll
    for (int off = 1; off < 64; off <<= 1) c += __shfl_xor(c, off, 64);
    __shared__ float sred[4];
    if ((threadIdx.x & 63) == 0) sred[threadIdx.x >> 6] = c;
    __syncthreads();
    if (threadIdx.x == 0) atomicAdd(out, sred[0] + sred[1] + sred[2] + sred[3]);
}

extern "C" void kernel_launch(void* const* d_in, const int* in_sizes, int n_in,
                              void* d_out, int out_size, void* d_ws, size_t ws_size,
                              hipStream_t stream) {
    const float* features = (const float*)d_in[0];
    const int*   labels   = (const int*)d_in[1];
    float* out = (float*)d_out;
    float* partials = (float*)d_ws;    // 16*4096*3*4 = 768 KB

    supcon_mfma<<<(NB / TI) * NCS, 512, 0, stream>>>(features, labels, partials, out);
    final_kernel<<<NB / 256, 256, 0, stream>>>(partials, out);
}

// Round 17
// 18.728 us; speedup vs baseline: 1.1866x; 1.1866x over previous
//
#include <hip/hip_runtime.h>
#include <math.h>

#define NB 4096
#define ND 128
#define TT 256        // tile size; K = ND = 128 staged whole
#define NT (NB / TT)  // 16 tiles per dimension; grid = 256 = 1 block/CU

typedef __bf16 bf16x8 __attribute__((ext_vector_type(8)));
typedef float  f32x4  __attribute__((ext_vector_type(4)));

// ---- pass 1: fused normalize + 256x256 LDS sim-tile + MFMA + stats ----------
// Verified-optimal configuration (R12, reproduced R15): 16 waves (1024 thr),
// wr = wid>>1 (8 x 32 i-rows, it=2), wc = wid&1 (2 x 128 j-cols, jt=8).
// Each block re-normalizes its two row-tiles f32->bf16 while staging to LDS
// (deterministic recompute; no fnb buffer, no extra dispatch boundary).
// LDS layout (16B chunks): (row, c16) -> slot row*16 + (c16 ^ (row&15))
//   -> conflict-free on both the staging write and the fragment read.
// Swapped MFMA operands: acc = mfma(j_frag, i_frag) so D col (lane&15) = i
// index -> row stats accumulate in-thread; cross-lane reduce = offsets 16/32.
// Measured-rejected alternatives: it=4@1024thr spills (R9); 8 waves (R13);
// diagonal-branch + interleaved staging (R14); fp8 + 2 blocks/CU (R16);
// cooperative grid.sync fusion (R8); atomic-fence single-pass (R3).
__global__ __launch_bounds__(1024) void supcon_mfma(
    const float* __restrict__ f, const int* __restrict__ labels,
    float* __restrict__ partials, float* __restrict__ out)
{
    __shared__ __align__(16) __bf16 At[TT * ND];   // 64 KB (i rows)
    __shared__ __align__(16) __bf16 Bt[TT * ND];   // 64 KB (j rows)
    __shared__ float redL[2][TT][3];               // 6 KB

    const int t    = threadIdx.x;
    const int lane = t & 63;
    const int wid  = t >> 6;            // 0..15
    const int wr   = wid >> 1;          // 0..7 : i rows wr*32 .. +32
    const int wc   = wid & 1;           // 0..1 : j cols wc*128 .. +128
    const int bi   = blockIdx.x >> 4;   // i tile 0..15
    const int cs   = blockIdx.x & 15;   // j tile 0..15
    const int lr   = lane & 15;
    const int lk   = lane >> 4;
    const int ib   = bi * TT;
    const int jb   = cs * TT;

    if (blockIdx.x == 0 && t == 0) out[0] = 0.f;   // target of final's atomics

    // ---- stage + normalize both tiles (f32 -> bf16, XOR-swizzled) -----------
    {
        const int c16  = t & 15;        // 16B-chunk index within row
        const int rloc = t >> 4;        // 0..63
        const float* gA = f + (size_t)ib * ND;
        const float* gB = f + (size_t)jb * ND;
#pragma unroll
        for (int s = 0; s < 2; ++s) {
            const float* g = s ? gB : gA;
            __bf16*      T = s ? Bt : At;
#pragma unroll
            for (int p = 0; p < 4; ++p) {
                const int row = p * 64 + rloc;
                const float4 lo = *reinterpret_cast<const float4*>(g + row * ND + c16 * 8);
                const float4 hi = *reinterpret_cast<const float4*>(g + row * ND + c16 * 8 + 4);
                float ss = lo.x*lo.x + lo.y*lo.y + lo.z*lo.z + lo.w*lo.w
                         + hi.x*hi.x + hi.y*hi.y + hi.z*hi.z + hi.w*hi.w;
#pragma unroll
                for (int off = 1; off < 16; off <<= 1) ss += __shfl_xor(ss, off, 64);
                const float inv = 1.0f / fmaxf(sqrtf(ss), 1e-12f);
                bf16x8 o;
                o[0] = (__bf16)(lo.x * inv); o[1] = (__bf16)(lo.y * inv);
                o[2] = (__bf16)(lo.z * inv); o[3] = (__bf16)(lo.w * inv);
                o[4] = (__bf16)(hi.x * inv); o[5] = (__bf16)(hi.y * inv);
                o[6] = (__bf16)(hi.z * inv); o[7] = (__bf16)(hi.w * inv);
                *reinterpret_cast<bf16x8*>(&T[(row * 16 + (c16 ^ (row & 15))) * 8]) = o;
            }
        }
    }

    // my i indices / labels (overlap staging latency)
    int ig[2], labi[2];
#pragma unroll
    for (int it = 0; it < 2; ++it) {
        ig[it]   = ib + wr * 32 + it * 16 + lr;   // D col = lane&15
        labi[it] = labels[ig[it]];
    }

    __syncthreads();

    // preload i-side fragments (MFMA B operand)
    bf16x8 bfr[2][4];
#pragma unroll
    for (int it = 0; it < 2; ++it)
#pragma unroll
        for (int ks = 0; ks < 4; ++ks) {
            const int row = wr * 32 + it * 16 + lr;
            bfr[it][ks] = *reinterpret_cast<const bf16x8*>(
                &At[(row * 16 + ((ks * 4 + lk) ^ lr)) * 8]);
        }

    float es[2] = {}, ps[2] = {}, np[2] = {};

#pragma unroll
    for (int jt = 0; jt < 8; ++jt) {
        // j-side fragments (MFMA A operand)
        bf16x8 af[4];
#pragma unroll
        for (int ks = 0; ks < 4; ++ks) {
            const int row = wc * 128 + jt * 16 + lr;
            af[ks] = *reinterpret_cast<const bf16x8*>(
                &Bt[(row * 16 + ((ks * 4 + lk) ^ lr)) * 8]);
        }
        f32x4 acc[2] = {};
#pragma unroll
        for (int ks = 0; ks < 4; ++ks)
#pragma unroll
            for (int it = 0; it < 2; ++it)
                acc[it] = __builtin_amdgcn_mfma_f32_16x16x32_bf16(
                    af[ks], bfr[it][ks], acc[it], 0, 0, 0);

        // j labels for this 16-tile: contiguous int4 per lk group
        const int jg0 = jb + wc * 128 + jt * 16 + lk * 4;   // D row = lk*4 + r
        const int4 lj4 = *reinterpret_cast<const int4*>(&labels[jg0]);
        const int lj[4] = {lj4.x, lj4.y, lj4.z, lj4.w};

        // epilogue: D[row = j-local = lk*4+r][col = i-local = lr]
#pragma unroll
        for (int it = 0; it < 2; ++it)
#pragma unroll
            for (int r = 0; r < 4; ++r) {
                const int   jgv  = jg0 + r;
                const float s    = acc[it][r];
                const float e    = __expf(s);
                const bool  self = (jgv == ig[it]);
                const bool  pos  = (lj[r] == labi[it]) && !self;
                es[it] += self ? 0.f : e;
                ps[it] += pos ? s : 0.f;
                np[it] += pos ? 1.f : 0.f;
            }
    }

    // cross-lane reduce over the 4 lk-groups only (offsets 16, 32)
#pragma unroll
    for (int off = 16; off < 64; off <<= 1)
#pragma unroll
        for (int it = 0; it < 2; ++it) {
            es[it] += __shfl_xor(es[it], off, 64);
            ps[it] += __shfl_xor(ps[it], off, 64);
            np[it] += __shfl_xor(np[it], off, 64);
        }
    if (lk == 0) {
#pragma unroll
        for (int it = 0; it < 2; ++it) {
            const int rl = wr * 32 + it * 16 + lr;
            redL[wc][rl][0] = es[it];
            redL[wc][rl][1] = ps[it];
            redL[wc][rl][2] = np[it];
        }
    }
    __syncthreads();
    if (t < TT) {   // fold the 2 col-halves; one deterministic writer per (cs,row)
        float* p = partials + ((size_t)cs * NB + ib + t) * 3;
        p[0] = redL[0][t][0] + redL[1][t][0];
        p[1] = redL[0][t][1] + redL[1][t][1];
        p[2] = redL[0][t][2] + redL[1][t][2];
    }
}

// ---- pass 2: per-row loss + block-level reduce + atomic to out --------------
__global__ __launch_bounds__(256) void final_kernel(
    const float* __restrict__ partials, float* __restrict__ out)
{
    const int row = blockIdx.x * 256 + threadIdx.x;
    float es = 0.f, ps = 0.f, np = 0.f;
#pragma unroll
    for (int cs = 0; cs < NT; ++cs) {
        const float* p = partials + ((size_t)cs * NB + row) * 3;
        es += p[0]; ps += p[1]; np += p[2];
    }
    const float lse = logf(es);
    float c = -(ps - np * lse) / ((np + 1e-5f) * (float)NB);
#pragma unroll
    for (int off = 1; off < 64; off <<= 1) c += __shfl_xor(c, off, 64);
    __shared__ float sred[4];
    if ((threadIdx.x & 63) == 0) sred[threadIdx.x >> 6] = c;
    __syncthreads();
    if (threadIdx.x == 0) atomicAdd(out, sred[0] + sred[1] + sred[2] + sred[3]);
}

extern "C" void kernel_launch(void* const* d_in, const int* in_sizes, int n_in,
                              void* d_out, int out_size, void* d_ws, size_t ws_size,
                              hipStream_t stream) {
    const float* features = (const float*)d_in[0];
    const int*   labels   = (const int*)d_in[1];
    float* out = (float*)d_out;
    float* partials = (float*)d_ws;    // 16*4096*3*4 = 768 KB

    supcon_mfma<<<NT * NT, 1024, 0, stream>>>(features, labels, partials, out);
    final_kernel<<<NB / 256, 256, 0, stream>>>(partials, out);
}